// Round 1
// baseline (940.027 us; speedup 1.0000x reference)
//
#include <hip/hip_runtime.h>
#include <hip/hip_bf16.h>

#define N_ROWS 32768
#define DQ 512
#define DC 2048
#define KDIM 2048

typedef float f32x4 __attribute__((ext_vector_type(4)));
typedef short bf16x8 __attribute__((ext_vector_type(8)));

// ---------------------------------------------------------------------------
// Pack W_block [2048,2048] row-major bf16: W_blk[o][i] = sgn(ob,ib) * W_{ob^ib}[o&511][i&511]
// sign mask bit (ob*4+ib): negative. Verified vs reference Hamilton rows:
//  ob0: +r -i -j -k | ob1: +i +r +k -j | ob2: +j -k +r +i | ob3: +k +j -i +r
// ---------------------------------------------------------------------------
__global__ void pack_w_kernel(const float* __restrict__ Wr, const float* __restrict__ Wi,
                              const float* __restrict__ Wj, const float* __restrict__ Wk,
                              __hip_bfloat16* __restrict__ Wblk) {
    int idx = blockIdx.x * blockDim.x + threadIdx.x;   // 2048*2048/4 threads
    int base = idx * 4;
    int o = base >> 11;
    int i = base & 2047;
    int ob = o >> 9, ib = i >> 9;
    int oo = o & 511, ii = i & 511;
    int s = ob ^ ib;
    const float* src = (s == 0) ? Wr : (s == 1) ? Wi : (s == 2) ? Wj : Wk;
    float sgn = ((0x428E >> (ob * 4 + ib)) & 1) ? -1.0f : 1.0f;
    float4 v = *(const float4*)(src + oo * 512 + ii);
    __hip_bfloat16 outv[4];
    outv[0] = __float2bfloat16(sgn * v.x);
    outv[1] = __float2bfloat16(sgn * v.y);
    outv[2] = __float2bfloat16(sgn * v.z);
    outv[3] = __float2bfloat16(sgn * v.w);
    *(uint2*)(Wblk + base) = *(uint2*)outv;
}

__global__ void pack_bias_kernel(const float* __restrict__ b1r, const float* __restrict__ b1i,
                                 const float* __restrict__ b1j, const float* __restrict__ b1k,
                                 const float* __restrict__ b2r, const float* __restrict__ b2i,
                                 const float* __restrict__ b2j, const float* __restrict__ b2k,
                                 float* __restrict__ b1full, float* __restrict__ b2full) {
    int idx = blockIdx.x * blockDim.x + threadIdx.x;   // 2048 threads
    int c = idx >> 9, d = idx & 511;
    const float* s1 = (c == 0) ? b1r : (c == 1) ? b1i : (c == 2) ? b1j : b1k;
    const float* s2 = (c == 0) ? b2r : (c == 1) ? b2i : (c == 2) ? b2j : b2k;
    b1full[idx] = s1[d];
    b2full[idx] = s2[d];
}

// x_cat[n][c*512+d] = q_c[n][d], fp32 -> bf16. 8 elems/thread; one wave spans
// exactly one 512-col component region -> fully coalesced.
__global__ void pack_x_kernel(const float* __restrict__ qr, const float* __restrict__ qi,
                              const float* __restrict__ qj, const float* __restrict__ qk,
                              __hip_bfloat16* __restrict__ xcat) {
    int idx = blockIdx.x * blockDim.x + threadIdx.x;   // N_ROWS*DC/8 threads
    size_t base = (size_t)idx * 8;
    int col = (int)(base & 2047);
    size_t n = base >> 11;
    int c = col >> 9, d = col & 511;
    const float* src = (c == 0) ? qr : (c == 1) ? qi : (c == 2) ? qj : qk;
    const float* p = src + n * 512 + d;
    float4 v0 = *(const float4*)(p);
    float4 v1 = *(const float4*)(p + 4);
    __hip_bfloat16 o[8];
    o[0] = __float2bfloat16(v0.x); o[1] = __float2bfloat16(v0.y);
    o[2] = __float2bfloat16(v0.z); o[3] = __float2bfloat16(v0.w);
    o[4] = __float2bfloat16(v1.x); o[5] = __float2bfloat16(v1.y);
    o[6] = __float2bfloat16(v1.z); o[7] = __float2bfloat16(v1.w);
    *(uint4*)(xcat + base) = *(uint4*)o;
}

// ---------------------------------------------------------------------------
// 256x256-tile 8-phase BT GEMM: C[M,2048] = A[M,2048] @ B[2048,2048]^T
// 8 waves (2M x 4N), BK=64, 2 dbuf x 4 half-tile regions (Alo,Ahi,Blo,Bhi),
// 128 KiB LDS. Counted vmcnt(4) once per K-tile (raw s_barrier, no drain).
// LDS swizzle: cb ^= ((row&7)<<4), applied on the global SOURCE address
// (global_load_lds writes linearly) and on the LDS read offset.
// Per K-tile phases: P1 (Mlo,Nlo): read A-Mlo(8)+B-Nlo(4), stage (u+1).Alo
//                    P2 (Mlo,Nhi): read B-Nhi(4),           stage (u+1).Ahi
//                    P3 (Mhi,Nhi): read A-Mhi(8),           stage (u+2).Blo
//                    P4 (Mhi,Nlo): no ds reads (bl held),   stage (u+2).Bhi + vmcnt(4)
// MODE 0: C = relu(acc+bias) -> bf16 row-major [M, 2048]
// MODE 1: C = acc+bias -> fp32 scattered into 4 blocks of [M,512] (d_out layout)
// ---------------------------------------------------------------------------
template <int MODE>
__global__ __launch_bounds__(512, 2) void qgemm8_kernel(
    const __hip_bfloat16* __restrict__ A,
    const __hip_bfloat16* __restrict__ B,
    const float* __restrict__ bias,
    void* __restrict__ Cout, int M)
{
    constexpr int NT = KDIM / 64;               // 32 K-tiles
    __shared__ short lds[2][4][8192];           // 128 KiB

    const int t = threadIdx.x;
    const int lane = t & 63;
    const int wv = t >> 6;
    const int wrow = wv >> 2;                   // 0..1 -> A region
    const int wcol = wv & 3;                    // 0..3 -> B region (wcol>>1)
    const int lm = lane & 15;

    const int m0 = blockIdx.y * 256;
    const int n0 = blockIdx.x * 256;

    const short* Ag = (const short*)A;
    const short* Bg = (const short*)B;

    // per-lane swizzled LDS column offsets (shorts) for ks=0,1
    const int swzb = (lane & 7) << 4;
    const int cbs0 = ((((lane >> 4) << 4)) ^ swzb) >> 1;
    const int cbs1 = ((64 + ((lane >> 4) << 4)) ^ swzb) >> 1;

    // staging geometry: wave covers rows [wv*8, wv*8+8) per issue, 2 issues/half-tile
    const int srow = (wv << 3) + (lane >> 3);
    const int secol = ((lane & 7) ^ (lane >> 3)) << 3;   // pre-swizzled source col (elems)

    auto STAGE = [&](const short* G, int grow, int kk, short* region) {
        const short* g0 = G + (size_t)(grow + srow) * KDIM + kk + secol;
        __builtin_amdgcn_global_load_lds(
            (const __attribute__((address_space(1))) void*)g0,
            (__attribute__((address_space(3))) void*)(region + wv * 512), 16, 0, 0);
        __builtin_amdgcn_global_load_lds(
            (const __attribute__((address_space(1))) void*)(g0 + (size_t)64 * KDIM),
            (__attribute__((address_space(3))) void*)(region + 4096 + wv * 512), 16, 0, 0);
    };

    f32x4 acc[8][4] = {};
    bf16x8 af[2][4], bl[2][2], bh[2][2];

    // prologue: tile0 all halves + tile1 B halves; first 8 loads (tile0) must land
    STAGE(Ag, m0, 0, lds[0][0]);
    STAGE(Ag, m0 + 128, 0, lds[0][1]);
    STAGE(Bg, n0, 0, lds[0][2]);
    STAGE(Bg, n0 + 128, 0, lds[0][3]);
    STAGE(Bg, n0, 64, lds[1][2]);
    STAGE(Bg, n0 + 128, 64, lds[1][3]);
    asm volatile("s_waitcnt vmcnt(4)" ::: "memory");
    __builtin_amdgcn_s_barrier();

    for (int u = 0; u < NT; ++u) {
        const int b = u & 1;
        const short* aR = lds[b][wrow];
        const short* bR = lds[b][2 + (wcol >> 1)];
        const int kk = u * 64;
        const int rBb = (wcol & 1) * 64;

        // ---------------- P1: (Mlo, Nlo) ----------------
#pragma unroll
        for (int mi = 0; mi < 4; mi++) {
            const short* p = aR + (mi * 16 + lm) * 64;
            af[0][mi] = *(const bf16x8*)(p + cbs0);
            af[1][mi] = *(const bf16x8*)(p + cbs1);
        }
#pragma unroll
        for (int ni = 0; ni < 2; ni++) {
            const short* p = bR + (rBb + ni * 16 + lm) * 64;
            bl[0][ni] = *(const bf16x8*)(p + cbs0);
            bl[1][ni] = *(const bf16x8*)(p + cbs1);
        }
        if (u < NT - 1) STAGE(Ag, m0, kk + 64, lds[b ^ 1][0]);
        __builtin_amdgcn_s_barrier();
        __builtin_amdgcn_s_setprio(1);
#pragma unroll
        for (int ks = 0; ks < 2; ks++)
#pragma unroll
            for (int mi = 0; mi < 4; mi++)
#pragma unroll
                for (int ni = 0; ni < 2; ni++)
                    acc[mi][ni] = __builtin_amdgcn_mfma_f32_16x16x32_bf16(
                        af[ks][mi], bl[ks][ni], acc[mi][ni], 0, 0, 0);
        __builtin_amdgcn_s_setprio(0);
        __builtin_amdgcn_s_barrier();

        // ---------------- P2: (Mlo, Nhi) ----------------
#pragma unroll
        for (int ni = 0; ni < 2; ni++) {
            const short* p = bR + (rBb + 32 + ni * 16 + lm) * 64;
            bh[0][ni] = *(const bf16x8*)(p + cbs0);
            bh[1][ni] = *(const bf16x8*)(p + cbs1);
        }
        if (u < NT - 1) STAGE(Ag, m0 + 128, kk + 64, lds[b ^ 1][1]);
        __builtin_amdgcn_s_barrier();
        __builtin_amdgcn_s_setprio(1);
#pragma unroll
        for (int ks = 0; ks < 2; ks++)
#pragma unroll
            for (int mi = 0; mi < 4; mi++)
#pragma unroll
                for (int ni = 0; ni < 2; ni++)
                    acc[mi][2 + ni] = __builtin_amdgcn_mfma_f32_16x16x32_bf16(
                        af[ks][mi], bh[ks][ni], acc[mi][2 + ni], 0, 0, 0);
        __builtin_amdgcn_s_setprio(0);
        __builtin_amdgcn_s_barrier();

        // ---------------- P3: (Mhi, Nhi) ----------------
#pragma unroll
        for (int mi = 0; mi < 4; mi++) {
            const short* p = aR + (64 + mi * 16 + lm) * 64;
            af[0][mi] = *(const bf16x8*)(p + cbs0);
            af[1][mi] = *(const bf16x8*)(p + cbs1);
        }
        if (u < NT - 2) STAGE(Bg, n0, kk + 128, lds[b][2]);
        __builtin_amdgcn_s_barrier();
        __builtin_amdgcn_s_setprio(1);
#pragma unroll
        for (int ks = 0; ks < 2; ks++)
#pragma unroll
            for (int mi = 0; mi < 4; mi++)
#pragma unroll
                for (int ni = 0; ni < 2; ni++)
                    acc[4 + mi][2 + ni] = __builtin_amdgcn_mfma_f32_16x16x32_bf16(
                        af[ks][mi], bh[ks][ni], acc[4 + mi][2 + ni], 0, 0, 0);
        __builtin_amdgcn_s_setprio(0);
        __builtin_amdgcn_s_barrier();

        // ---------------- P4: (Mhi, Nlo) — no ds reads (bl held in regs) ----------------
        if (u < NT - 2) STAGE(Bg, n0 + 128, kk + 128, lds[b][3]);
        __builtin_amdgcn_s_barrier();
        __builtin_amdgcn_s_setprio(1);
#pragma unroll
        for (int ks = 0; ks < 2; ks++)
#pragma unroll
            for (int mi = 0; mi < 4; mi++)
#pragma unroll
                for (int ni = 0; ni < 2; ni++)
                    acc[4 + mi][ni] = __builtin_amdgcn_mfma_f32_16x16x32_bf16(
                        af[ks][mi], bl[ks][ni], acc[4 + mi][ni], 0, 0, 0);
        __builtin_amdgcn_s_setprio(0);
        // once-per-tile checkpoint: keep next tile's B halves (4 loads) in flight;
        // at the tail drain fully so the last tiles' stages are visible.
        if (u < NT - 2)      { asm volatile("s_waitcnt vmcnt(4)" ::: "memory"); }
        else if (u == NT - 2){ asm volatile("s_waitcnt vmcnt(0)" ::: "memory"); }
        __builtin_amdgcn_s_barrier();
    }

    // epilogue: C row = (lane>>4)*4 + r (+tile offsets), col = lane&15 (+tile offsets)
#pragma unroll
    for (int mi8 = 0; mi8 < 8; mi8++) {
#pragma unroll
        for (int ni4 = 0; ni4 < 4; ni4++) {
            const int n_g = n0 + wcol * 64 + ni4 * 16 + lm;
            const float bia = bias[n_g];
#pragma unroll
            for (int r = 0; r < 4; r++) {
                const int m_g = m0 + wrow * 128 + (mi8 >> 2) * 64 + (mi8 & 3) * 16 + (lane >> 4) * 4 + r;
                float v = acc[mi8][ni4][r] + bia;
                if (MODE == 0) {
                    v = fmaxf(v, 0.0f);
                    ((__hip_bfloat16*)Cout)[(size_t)m_g * DC + n_g] = __float2bfloat16(v);
                } else {
                    const int c = n_g >> 9, d = n_g & 511;
                    ((float*)Cout)[(size_t)c * ((size_t)M * DQ) + (size_t)m_g * DQ + d] = v;
                }
            }
        }
    }
}

extern "C" void kernel_launch(void* const* d_in, const int* in_sizes, int n_in,
                              void* d_out, int out_size, void* d_ws, size_t ws_size,
                              hipStream_t stream) {
    const float* qr = (const float*)d_in[0];
    const float* qi = (const float*)d_in[1];
    const float* qj = (const float*)d_in[2];
    const float* qk = (const float*)d_in[3];
    const float* W1r = (const float*)d_in[4];
    const float* W1i = (const float*)d_in[5];
    const float* W1j = (const float*)d_in[6];
    const float* W1k = (const float*)d_in[7];
    const float* W2r = (const float*)d_in[8];
    const float* W2i = (const float*)d_in[9];
    const float* W2j = (const float*)d_in[10];
    const float* W2k = (const float*)d_in[11];
    const float* b1r = (const float*)d_in[12];
    const float* b1i = (const float*)d_in[13];
    const float* b1j = (const float*)d_in[14];
    const float* b1k = (const float*)d_in[15];
    const float* b2r = (const float*)d_in[16];
    const float* b2i = (const float*)d_in[17];
    const float* b2j = (const float*)d_in[18];
    const float* b2k = (const float*)d_in[19];

    char* ws = (char*)d_ws;
    __hip_bfloat16* W1blk = (__hip_bfloat16*)ws;                       // 8 MiB
    __hip_bfloat16* W2blk = (__hip_bfloat16*)(ws + (8u << 20));        // 8 MiB
    float* b1full = (float*)(ws + (16u << 20));                        // 8 KiB
    float* b2full = b1full + 2048;                                     // 8 KiB
    __hip_bfloat16* xcat = (__hip_bfloat16*)(ws + (16u << 20) + 65536); // 128 MiB
    __hip_bfloat16* H = xcat + (size_t)N_ROWS * DC;                    // 128 MiB

    pack_w_kernel<<<(2048 * 2048 / 4) / 256, 256, 0, stream>>>(W1r, W1i, W1j, W1k, W1blk);
    pack_w_kernel<<<(2048 * 2048 / 4) / 256, 256, 0, stream>>>(W2r, W2i, W2j, W2k, W2blk);
    pack_bias_kernel<<<8, 256, 0, stream>>>(b1r, b1i, b1j, b1k, b2r, b2i, b2j, b2k, b1full, b2full);
    pack_x_kernel<<<(N_ROWS * (size_t)DC / 8) / 256, 256, 0, stream>>>(qr, qi, qj, qk, xcat);

    // grid: 8 N-tiles (fastest) x 128 M-tiles. gridDim.x == 8 == #XCDs -> natural
    // round-robin dispatch pins one 1-MB B-panel per XCD L2 while A streams.
    dim3 grid(DC / 256, N_ROWS / 256);
    qgemm8_kernel<0><<<grid, 512, 0, stream>>>(xcat, W1blk, b1full, (void*)H, N_ROWS);
    qgemm8_kernel<1><<<grid, 512, 0, stream>>>(H, W2blk, b2full, d_out, N_ROWS);
}

// Round 2
// 935.602 us; speedup vs baseline: 1.0047x; 1.0047x over previous
//
#include <hip/hip_runtime.h>
#include <hip/hip_bf16.h>

#define N_ROWS 32768
#define DQ 512
#define DC 2048
#define KDIM 2048

typedef float f32x4 __attribute__((ext_vector_type(4)));
typedef short bf16x8 __attribute__((ext_vector_type(8)));

// ---------------------------------------------------------------------------
// Pack W_block [2048,2048] row-major bf16: W_blk[o][i] = sgn(ob,ib) * W_{ob^ib}[o&511][i&511]
// sign mask bit (ob*4+ib): negative. Verified vs reference Hamilton rows:
//  ob0: +r -i -j -k | ob1: +i +r +k -j | ob2: +j -k +r +i | ob3: +k +j -i +r
// ---------------------------------------------------------------------------
__global__ void pack_w_kernel(const float* __restrict__ Wr, const float* __restrict__ Wi,
                              const float* __restrict__ Wj, const float* __restrict__ Wk,
                              __hip_bfloat16* __restrict__ Wblk) {
    int idx = blockIdx.x * blockDim.x + threadIdx.x;   // 2048*2048/4 threads
    int base = idx * 4;
    int o = base >> 11;
    int i = base & 2047;
    int ob = o >> 9, ib = i >> 9;
    int oo = o & 511, ii = i & 511;
    int s = ob ^ ib;
    const float* src = (s == 0) ? Wr : (s == 1) ? Wi : (s == 2) ? Wj : Wk;
    float sgn = ((0x428E >> (ob * 4 + ib)) & 1) ? -1.0f : 1.0f;
    float4 v = *(const float4*)(src + oo * 512 + ii);
    __hip_bfloat16 outv[4];
    outv[0] = __float2bfloat16(sgn * v.x);
    outv[1] = __float2bfloat16(sgn * v.y);
    outv[2] = __float2bfloat16(sgn * v.z);
    outv[3] = __float2bfloat16(sgn * v.w);
    *(uint2*)(Wblk + base) = *(uint2*)outv;
}

__global__ void pack_bias_kernel(const float* __restrict__ b1r, const float* __restrict__ b1i,
                                 const float* __restrict__ b1j, const float* __restrict__ b1k,
                                 const float* __restrict__ b2r, const float* __restrict__ b2i,
                                 const float* __restrict__ b2j, const float* __restrict__ b2k,
                                 float* __restrict__ b1full, float* __restrict__ b2full) {
    int idx = blockIdx.x * blockDim.x + threadIdx.x;   // 2048 threads
    int c = idx >> 9, d = idx & 511;
    const float* s1 = (c == 0) ? b1r : (c == 1) ? b1i : (c == 2) ? b1j : b1k;
    const float* s2 = (c == 0) ? b2r : (c == 1) ? b2i : (c == 2) ? b2j : b2k;
    b1full[idx] = s1[d];
    b2full[idx] = s2[d];
}

// x_cat[n][c*512+d] = q_c[n][d], fp32 -> bf16. 8 elems/thread; one wave spans
// exactly one 512-col component region -> fully coalesced.
__global__ void pack_x_kernel(const float* __restrict__ qr, const float* __restrict__ qi,
                              const float* __restrict__ qj, const float* __restrict__ qk,
                              __hip_bfloat16* __restrict__ xcat) {
    int idx = blockIdx.x * blockDim.x + threadIdx.x;   // N_ROWS*DC/8 threads
    size_t base = (size_t)idx * 8;
    int col = (int)(base & 2047);
    size_t n = base >> 11;
    int c = col >> 9, d = col & 511;
    const float* src = (c == 0) ? qr : (c == 1) ? qi : (c == 2) ? qj : qk;
    const float* p = src + n * 512 + d;
    float4 v0 = *(const float4*)(p);
    float4 v1 = *(const float4*)(p + 4);
    __hip_bfloat16 o[8];
    o[0] = __float2bfloat16(v0.x); o[1] = __float2bfloat16(v0.y);
    o[2] = __float2bfloat16(v0.z); o[3] = __float2bfloat16(v0.w);
    o[4] = __float2bfloat16(v1.x); o[5] = __float2bfloat16(v1.y);
    o[6] = __float2bfloat16(v1.z); o[7] = __float2bfloat16(v1.w);
    *(uint4*)(xcat + base) = *(uint4*)o;
}

// ---------------------------------------------------------------------------
// 256x256-tile BT GEMM: C[M,2048] = A[M,2048] @ B[2048,2048]^T
// 8 waves (2M x 4N), BK=64, 2 dbuf x 4 half-tile regions (Alo,Ahi,Blo,Bhi),
// 128 KiB LDS. TWO barriers per K-tile (cluster1 = Mlo row, cluster2 = Mhi row)
// -- all stage->read / read->overwrite hazards are >=1 barrier separated because
// ds_reads drain (lgkmcnt) before the same cluster's MFMAs, which precede the
// cluster-end barrier. Free-running waves within a cluster overlap one wave's
// LDS reads / staging with another's MFMAs (m114 implicit overlap).
// Counted vmcnt(4) once per K-tile: leaves B(u+2)'s 4 loads in flight, drains
// A(u+1)+B(u+1). LDS swizzle: col ^= ((lane&7)<<4) bytes, applied on the global
// SOURCE address (global_load_lds writes linearly) and on the LDS read offset.
// MODE 0: C = relu(acc+bias) -> bf16 row-major [M, 2048]
// MODE 1: C = acc+bias -> fp32 scattered into 4 blocks of [M,512] (d_out layout)
// ---------------------------------------------------------------------------
template <int MODE>
__global__ __launch_bounds__(512, 2) void qgemm8_kernel(
    const __hip_bfloat16* __restrict__ A,
    const __hip_bfloat16* __restrict__ B,
    const float* __restrict__ bias,
    void* __restrict__ Cout, int M)
{
    constexpr int NT = KDIM / 64;               // 32 K-tiles
    __shared__ short lds[2][4][8192];           // 128 KiB

    const int t = threadIdx.x;
    const int lane = t & 63;
    const int wv = t >> 6;
    const int wrow = wv >> 2;                   // 0..1 -> A region
    const int wcol = wv & 3;                    // 0..3 -> B region (wcol>>1)
    const int lm = lane & 15;

    const int m0 = blockIdx.y * 256;
    const int n0 = blockIdx.x * 256;

    const short* Ag = (const short*)A;
    const short* Bg = (const short*)B;

    // per-lane swizzled LDS column offsets (shorts) for ks=0,1
    const int swzb = (lane & 7) << 4;
    const int cbs0 = ((((lane >> 4) << 4)) ^ swzb) >> 1;
    const int cbs1 = ((64 + ((lane >> 4) << 4)) ^ swzb) >> 1;

    // staging geometry: wave covers rows [wv*8, wv*8+8) per issue, 2 issues/half-tile
    const int srow = (wv << 3) + (lane >> 3);
    const int secol = ((lane & 7) ^ (lane >> 3)) << 3;   // pre-swizzled source col (elems)

    auto STAGE = [&](const short* G, int grow, int kk, short* region) {
        const short* g0 = G + (size_t)(grow + srow) * KDIM + kk + secol;
        __builtin_amdgcn_global_load_lds(
            (const __attribute__((address_space(1))) void*)g0,
            (__attribute__((address_space(3))) void*)(region + wv * 512), 16, 0, 0);
        __builtin_amdgcn_global_load_lds(
            (const __attribute__((address_space(1))) void*)(g0 + (size_t)64 * KDIM),
            (__attribute__((address_space(3))) void*)(region + 4096 + wv * 512), 16, 0, 0);
    };

    f32x4 acc[8][4] = {};
    bf16x8 af[2][4], bl[2][2], bh[2][2];

    // prologue: tile0 all halves + tile1 B halves; first 8 loads (tile0) must land
    STAGE(Ag, m0, 0, lds[0][0]);
    STAGE(Ag, m0 + 128, 0, lds[0][1]);
    STAGE(Bg, n0, 0, lds[0][2]);
    STAGE(Bg, n0 + 128, 0, lds[0][3]);
    STAGE(Bg, n0, 64, lds[1][2]);
    STAGE(Bg, n0 + 128, 64, lds[1][3]);
    asm volatile("s_waitcnt vmcnt(4)" ::: "memory");
    __builtin_amdgcn_s_barrier();

    for (int u = 0; u < NT; ++u) {
        const int b = u & 1;
        const short* aR = lds[b][wrow];
        const short* bR = lds[b][2 + (wcol >> 1)];
        const int kk = u * 64;
        const int rBb = (wcol & 1) * 64;

        // ========== cluster 1: (Mlo,Nlo) + (Mlo,Nhi) ==========
        // reads: af-lo (8) + bl (4) + bh (4); stage: A(u+1) both halves
#pragma unroll
        for (int mi = 0; mi < 4; mi++) {
            const short* p = aR + (mi * 16 + lm) * 64;
            af[0][mi] = *(const bf16x8*)(p + cbs0);
            af[1][mi] = *(const bf16x8*)(p + cbs1);
        }
#pragma unroll
        for (int ni = 0; ni < 2; ni++) {
            const short* p = bR + (rBb + ni * 16 + lm) * 64;
            bl[0][ni] = *(const bf16x8*)(p + cbs0);
            bl[1][ni] = *(const bf16x8*)(p + cbs1);
        }
#pragma unroll
        for (int ni = 0; ni < 2; ni++) {
            const short* p = bR + (rBb + 32 + ni * 16 + lm) * 64;
            bh[0][ni] = *(const bf16x8*)(p + cbs0);
            bh[1][ni] = *(const bf16x8*)(p + cbs1);
        }
        if (u < NT - 1) {
            STAGE(Ag, m0, kk + 64, lds[b ^ 1][0]);
            STAGE(Ag, m0 + 128, kk + 64, lds[b ^ 1][1]);
        }
        __builtin_amdgcn_s_setprio(1);
#pragma unroll
        for (int ks = 0; ks < 2; ks++)
#pragma unroll
            for (int mi = 0; mi < 4; mi++)
#pragma unroll
                for (int ni = 0; ni < 2; ni++)
                    acc[mi][ni] = __builtin_amdgcn_mfma_f32_16x16x32_bf16(
                        af[ks][mi], bl[ks][ni], acc[mi][ni], 0, 0, 0);
#pragma unroll
        for (int ks = 0; ks < 2; ks++)
#pragma unroll
            for (int mi = 0; mi < 4; mi++)
#pragma unroll
                for (int ni = 0; ni < 2; ni++)
                    acc[mi][2 + ni] = __builtin_amdgcn_mfma_f32_16x16x32_bf16(
                        af[ks][mi], bh[ks][ni], acc[mi][2 + ni], 0, 0, 0);
        __builtin_amdgcn_s_setprio(0);
        __builtin_amdgcn_s_barrier();

        // ========== cluster 2: (Mhi,Nlo) + (Mhi,Nhi) ==========
        // reads: af-hi (8); stage: B(u+2) both halves; bl/bh held in regs
#pragma unroll
        for (int mi = 0; mi < 4; mi++) {
            const short* p = aR + (64 + mi * 16 + lm) * 64;
            af[0][mi] = *(const bf16x8*)(p + cbs0);
            af[1][mi] = *(const bf16x8*)(p + cbs1);
        }
        if (u < NT - 2) {
            STAGE(Bg, n0, kk + 128, lds[b][2]);
            STAGE(Bg, n0 + 128, kk + 128, lds[b][3]);
        }
        __builtin_amdgcn_s_setprio(1);
#pragma unroll
        for (int ks = 0; ks < 2; ks++)
#pragma unroll
            for (int mi = 0; mi < 4; mi++)
#pragma unroll
                for (int ni = 0; ni < 2; ni++)
                    acc[4 + mi][ni] = __builtin_amdgcn_mfma_f32_16x16x32_bf16(
                        af[ks][mi], bl[ks][ni], acc[4 + mi][ni], 0, 0, 0);
#pragma unroll
        for (int ks = 0; ks < 2; ks++)
#pragma unroll
            for (int mi = 0; mi < 4; mi++)
#pragma unroll
                for (int ni = 0; ni < 2; ni++)
                    acc[4 + mi][2 + ni] = __builtin_amdgcn_mfma_f32_16x16x32_bf16(
                        af[ks][mi], bh[ks][ni], acc[4 + mi][2 + ni], 0, 0, 0);
        __builtin_amdgcn_s_setprio(0);
        // once-per-tile checkpoint: keep B(u+2)'s 4 loads in flight; drain
        // fully at the tail so the last tiles' stages are visible.
        if (u < NT - 2)      { asm volatile("s_waitcnt vmcnt(4)" ::: "memory"); }
        else if (u == NT - 2){ asm volatile("s_waitcnt vmcnt(0)" ::: "memory"); }
        __builtin_amdgcn_s_barrier();
    }

    // epilogue: C row = (lane>>4)*4 + r (+tile offsets), col = lane&15 (+tile offsets)
#pragma unroll
    for (int mi8 = 0; mi8 < 8; mi8++) {
#pragma unroll
        for (int ni4 = 0; ni4 < 4; ni4++) {
            const int n_g = n0 + wcol * 64 + ni4 * 16 + lm;
            const float bia = bias[n_g];
#pragma unroll
            for (int r = 0; r < 4; r++) {
                const int m_g = m0 + wrow * 128 + (mi8 >> 2) * 64 + (mi8 & 3) * 16 + (lane >> 4) * 4 + r;
                float v = acc[mi8][ni4][r] + bia;
                if (MODE == 0) {
                    v = fmaxf(v, 0.0f);
                    ((__hip_bfloat16*)Cout)[(size_t)m_g * DC + n_g] = __float2bfloat16(v);
                } else {
                    const int c = n_g >> 9, d = n_g & 511;
                    ((float*)Cout)[(size_t)c * ((size_t)M * DQ) + (size_t)m_g * DQ + d] = v;
                }
            }
        }
    }
}

extern "C" void kernel_launch(void* const* d_in, const int* in_sizes, int n_in,
                              void* d_out, int out_size, void* d_ws, size_t ws_size,
                              hipStream_t stream) {
    const float* qr = (const float*)d_in[0];
    const float* qi = (const float*)d_in[1];
    const float* qj = (const float*)d_in[2];
    const float* qk = (const float*)d_in[3];
    const float* W1r = (const float*)d_in[4];
    const float* W1i = (const float*)d_in[5];
    const float* W1j = (const float*)d_in[6];
    const float* W1k = (const float*)d_in[7];
    const float* W2r = (const float*)d_in[8];
    const float* W2i = (const float*)d_in[9];
    const float* W2j = (const float*)d_in[10];
    const float* W2k = (const float*)d_in[11];
    const float* b1r = (const float*)d_in[12];
    const float* b1i = (const float*)d_in[13];
    const float* b1j = (const float*)d_in[14];
    const float* b1k = (const float*)d_in[15];
    const float* b2r = (const float*)d_in[16];
    const float* b2i = (const float*)d_in[17];
    const float* b2j = (const float*)d_in[18];
    const float* b2k = (const float*)d_in[19];

    char* ws = (char*)d_ws;
    __hip_bfloat16* W1blk = (__hip_bfloat16*)ws;                       // 8 MiB
    __hip_bfloat16* W2blk = (__hip_bfloat16*)(ws + (8u << 20));        // 8 MiB
    float* b1full = (float*)(ws + (16u << 20));                        // 8 KiB
    float* b2full = b1full + 2048;                                     // 8 KiB
    __hip_bfloat16* xcat = (__hip_bfloat16*)(ws + (16u << 20) + 65536); // 128 MiB
    __hip_bfloat16* H = xcat + (size_t)N_ROWS * DC;                    // 128 MiB

    pack_w_kernel<<<(2048 * 2048 / 4) / 256, 256, 0, stream>>>(W1r, W1i, W1j, W1k, W1blk);
    pack_w_kernel<<<(2048 * 2048 / 4) / 256, 256, 0, stream>>>(W2r, W2i, W2j, W2k, W2blk);
    pack_bias_kernel<<<8, 256, 0, stream>>>(b1r, b1i, b1j, b1k, b2r, b2i, b2j, b2k, b1full, b2full);
    pack_x_kernel<<<(N_ROWS * (size_t)DC / 8) / 256, 256, 0, stream>>>(qr, qi, qj, qk, xcat);

    // grid: 8 N-tiles (fastest) x 128 M-tiles. gridDim.x == 8 == #XCDs -> natural
    // round-robin dispatch pins one 1-MB B-panel per XCD L2 while A streams.
    dim3 grid(DC / 256, N_ROWS / 256);
    qgemm8_kernel<0><<<grid, 512, 0, stream>>>(xcat, W1blk, b1full, (void*)H, N_ROWS);
    qgemm8_kernel<1><<<grid, 512, 0, stream>>>(H, W2blk, b2full, d_out, N_ROWS);
}